// Round 3
// baseline (230.481 us; speedup 1.0000x reference)
//
#include <hip/hip_runtime.h>

#define NS 4096
#define NCC 1024
#define DD 64
#define HH2 32
#define NSEQ 32
#define SLEN 256
#define SLOTS 8192
#define LNEPS 1e-3f
#define MAXSPS 1024   // max sites per sequence (mean 128 — huge margin)

// ---------------- K_setup: blocks 0-4 = prep (5120 rows), blocks 5-6 = counting sort ----------------
__global__ void __launch_bounds__(1024) k_setup(
    const float* __restrict__ sites, const float* __restrict__ cons,
    const float* __restrict__ Ws, const float* __restrict__ bs,
    const float* __restrict__ Wc, const float* __restrict__ bc,
    const float* __restrict__ Wd, const float* __restrict__ bd,
    const float* __restrict__ g, const float* __restrict__ Wo,
    float* __restrict__ u, float* __restrict__ A, float* __restrict__ P,
    float* __restrict__ v, float* __restrict__ B, float* __restrict__ Q,
    const int* __restrict__ idxl, const int* __restrict__ idxh,
    int* __restrict__ offl, int* __restrict__ slotl, int* __restrict__ sitel,
    int* __restrict__ offh, int* __restrict__ sloth, int* __restrict__ siteh) {
  __shared__ int cnt[SLOTS];
  __shared__ int wsumI[16];
  int tid = threadIdx.x;
  if (blockIdx.x < 5) {
    // ---- prep ----
    int t = blockIdx.x * 1024 + tid;
    if (t >= NS + NCC) return;
    bool isSite = t < NS;
    int row = isSite ? t : t - NS;
    const float* x = isSite ? sites + row * DD : cons + row * DD;
    const float* W1 = isSite ? Ws : Wc;
    const float* b1 = isSite ? bs : bc;
    float s[HH2];
#pragma unroll
    for (int h = 0; h < HH2; h++) s[h] = b1[h];
    for (int k = 0; k < DD; k++) {
      float xv = x[k];
#pragma unroll
      for (int h = 0; h < HH2; h++) s[h] = fmaf(xv, W1[k * HH2 + h], s[h]);
    }
#pragma unroll
    for (int h = 0; h < HH2; h++) s[h] = fmaxf(s[h], 0.0f);
    float hs[HH2];
#pragma unroll
    for (int h = 0; h < HH2; h++) hs[h] = isSite ? 0.0f : bd[h];  // b_d folded into con side
    for (int k = 0; k < HH2; k++) {
      float sv = s[k];
#pragma unroll
      for (int h = 0; h < HH2; h++) hs[h] = fmaf(sv, Wd[k * HH2 + h], hs[h]);
    }
    float mu = 0.f;
#pragma unroll
    for (int h = 0; h < HH2; h++) mu += hs[h];
    mu *= (1.0f / HH2);
    float p = 0.f, a = 0.f;
    float* dst = isSite ? (u + row * HH2) : (v + row * HH2);
#pragma unroll
    for (int h = 0; h < HH2; h++) {
      float uu = hs[h] - mu;
      dst[h] = uu;
      p += uu * uu;
      a = fmaf(uu * g[h], Wo[h], a);
    }
    p *= (1.0f / HH2);
    if (isSite) { A[row] = a; P[row] = p; } else { B[row] = a; Q[row] = p; }
    return;
  }
  // ---- sort (blocks 5,6) ----
  int lane = tid & 63, wv = tid >> 6;
  int pass = blockIdx.x - 5;
  const int* idx = pass ? idxh : idxl;
  int* off = pass ? offh : offl;
  int* slotA = pass ? sloth : slotl;
  int* siteA = pass ? siteh : sitel;
  for (int i2 = tid; i2 < SLOTS; i2 += 1024) cnt[i2] = 0;
  __syncthreads();
  for (int i2 = tid; i2 < NS; i2 += 1024) atomicAdd(&cnt[idx[i2]], 1);
  __syncthreads();
  int base = tid * 8;
  int loc[8]; int sum = 0;
#pragma unroll
  for (int q2 = 0; q2 < 8; q2++) { loc[q2] = sum; sum += cnt[base + q2]; }
  int incl = sum;
#pragma unroll
  for (int o = 1; o < 64; o <<= 1) { int t2 = __shfl_up(incl, o); if (lane >= o) incl += t2; }
  if (lane == 63) wsumI[wv] = incl;
  __syncthreads();
  int wprev = 0;
#pragma unroll
  for (int w = 0; w < 16; w++) { int t3 = wsumI[w]; if (w < wv) wprev += t3; }
  int excl = wprev + (incl - sum);
  __syncthreads();
#pragma unroll
  for (int q2 = 0; q2 < 8; q2++) { int o2 = excl + loc[q2]; off[base + q2] = o2; cnt[base + q2] = o2; }
  if (tid == 0) off[SLOTS] = NS;
  __syncthreads();
  for (int i2 = tid; i2 < NS; i2 += 1024) {
    int sl = idx[i2];
    int pos = atomicAdd(&cnt[sl], 1);
    slotA[pos] = sl; siteA[pos] = i2;
  }
}

// ---------------- K_main: logits -> softmax -> cumsums; 16 rows/block, 2 barriers total ----------------
__global__ void __launch_bounds__(1024) k_main(const float* __restrict__ u,
    const float* __restrict__ A, const float* __restrict__ P,
    const float* __restrict__ v, const float* __restrict__ B, const float* __restrict__ Q,
    const float* __restrict__ lnb, const float* __restrict__ Wo, const float* __restrict__ bo,
    float* __restrict__ M, float* __restrict__ CLp, float* __restrict__ CHp) {
  int j = threadIdx.x;
  int lane = j & 63, wv = j >> 6;
  __shared__ float redA[16 * 16];  // [row][wave]
  __shared__ float redB[16 * 16];
  float4 vv[8];
  const float4* vp = (const float4*)(v + j * HH2);
#pragma unroll
  for (int q = 0; q < 8; q++) vv[q] = vp[q];
  float Bj = B[j], Qj = Q[j];
  float C = bo[0];
#pragma unroll
  for (int k = 0; k < HH2; k++) C = fmaf(lnb[k], Wo[k], C);
  int row0 = blockIdx.x * 16;

  float logit[16];
  // Phase 1: all logits + per-wave max
#pragma unroll
  for (int rr = 0; rr < 16; rr++) {
    int i = row0 + rr;
    const float4* up = (const float4*)(u + i * HH2);
    float dot = 0.f;
#pragma unroll
    for (int q = 0; q < 8; q++) {
      float4 u4 = up[q];
      dot = fmaf(u4.x, vv[q].x, dot);
      dot = fmaf(u4.y, vv[q].y, dot);
      dot = fmaf(u4.z, vv[q].z, dot);
      dot = fmaf(u4.w, vv[q].w, dot);
    }
    float var = P[i] + Qj + dot * 0.0625f;   // P + Q + 2*dot/32
    float lg = rsqrtf(var + LNEPS) * (A[i] + Bj) + C;
    logit[rr] = lg;
    float mx = lg;
#pragma unroll
    for (int o = 32; o > 0; o >>= 1) mx = fmaxf(mx, __shfl_xor(mx, o));
    if (lane == 0) redA[rr * 16 + wv] = mx;
  }
  __syncthreads();
  // Phase 2: block max (vector LDS reads), exp, per-wave inclusive scan
  float e[16], incl[16];
#pragma unroll
  for (int rr = 0; rr < 16; rr++) {
    const float4* ra = (const float4*)(redA + rr * 16);
    float4 a0 = ra[0], a1 = ra[1], a2 = ra[2], a3 = ra[3];
    float mx = fmaxf(fmaxf(fmaxf(a0.x, a0.y), fmaxf(a0.z, a0.w)),
                     fmaxf(fmaxf(a1.x, a1.y), fmaxf(a1.z, a1.w)));
    mx = fmaxf(mx, fmaxf(fmaxf(fmaxf(a2.x, a2.y), fmaxf(a2.z, a2.w)),
                         fmaxf(fmaxf(a3.x, a3.y), fmaxf(a3.z, a3.w))));
    float ee = __expf(logit[rr] - mx);
    float ic = ee;
#pragma unroll
    for (int o = 1; o < 64; o <<= 1) { float tt = __shfl_up(ic, o); if (lane >= o) ic += tt; }
    if (lane == 63) redB[rr * 16 + wv] = ic;
    e[rr] = ee; incl[rr] = ic;
  }
  __syncthreads();
  // Phase 3: block prefix/total from wave sums, write M/CL/CH
#pragma unroll
  for (int rr = 0; rr < 16; rr++) {
    const float4* rb = (const float4*)(redB + rr * 16);
    float4 b0 = rb[0], b1 = rb[1], b2 = rb[2], b3 = rb[3];
    float w_[16] = {b0.x, b0.y, b0.z, b0.w, b1.x, b1.y, b1.z, b1.w,
                    b2.x, b2.y, b2.z, b2.w, b3.x, b3.y, b3.z, b3.w};
    float prev = 0.f, tot = 0.f;
#pragma unroll
    for (int w = 0; w < 16; w++) { tot += w_[w]; if (w < wv) prev += w_[w]; }
    float chE = prev + incl[rr];
    float rd = 1.0f / tot;
    int o_ = (row0 + rr) * NCC + j;
    M[o_] = e[rr] * rd;                    // softmax (to d_out)
    CHp[o_] = chE * rd;                    // forward cumsum
    CLp[o_] = (tot - chE + e[rr]) * rd;    // reverse cumsum
  }
}

// ---------------- K_band: walk sorted site list per (band, seq), write excl factors ----------------
// grid = (4 coltiles, 32 seqs, 2 bands), block = 64 threads x 4 cols (float4)
// Deep (D=12) rolling prefetch; site/slot lists staged in LDS.
__global__ void __launch_bounds__(64) k_band(const float* __restrict__ CLp, const float* __restrict__ CHp,
    const int* __restrict__ offl, const int* __restrict__ slotl, const int* __restrict__ sitel,
    const int* __restrict__ offh, const int* __restrict__ sloth, const int* __restrict__ siteh,
    float* __restrict__ EL, float* __restrict__ EH) {
  int band = blockIdx.z;
  const float* cum = band ? CHp : CLp;
  const int* off   = band ? offh : offl;
  const int* slotA = band ? sloth : slotl;
  const int* siteA = band ? siteh : sitel;
  float* E = band ? EH : EL;
  int seq = blockIdx.y;
  int j0 = blockIdx.x * 256 + threadIdx.x * 4;
  int s0 = off[seq * SLEN];
  int s1 = off[seq * SLEN + SLEN];
  int n = s1 - s0;

  __shared__ int s_site[MAXSPS];
  __shared__ int s_slot[MAXSPS];
  for (int i = threadIdx.x; i < n; i += 64) {
    s_site[i] = siteA[s0 + i];
    s_slot[i] = slotA[s0 + i];
  }
  __syncthreads();

  const int D = 12;
  float4 buf[D];
#pragma unroll
  for (int k = 0; k < D; k++)
    if (k < n) buf[k] = *(const float4*)(cum + (size_t)s_site[k] * NCC + j0);

  float4 r = make_float4(1.f, 1.f, 1.f, 1.f);
  float4 z = make_float4(0.f, 0.f, 0.f, 0.f);
  int prev = -1;
  for (int s = 0; s < n; s += D) {
#pragma unroll
    for (int k = 0; k < D; k++) {
      int cur = s + k;
      if (cur >= n) break;
      float4 cv = buf[k];
      int sp = cur + D;
      if (sp < n) buf[k] = *(const float4*)(cum + (size_t)s_site[sp] * NCC + j0);
      int slot = s_slot[cur];
      if (slot != prev) {
        if (prev >= 0) {
          r.x *= fmaxf(1.f - z.x, 0.f);
          r.y *= fmaxf(1.f - z.y, 0.f);
          r.z *= fmaxf(1.f - z.z, 0.f);
          r.w *= fmaxf(1.f - z.w, 0.f);
          z = make_float4(0.f, 0.f, 0.f, 0.f);
        }
        prev = slot;
      }
      *(float4*)(E + (size_t)s_site[cur] * NCC + j0) = r;  // exclusive cumprod at this slot
      z.x += cv.x; z.y += cv.y; z.z += cv.z; z.w += cv.w;
    }
  }
}

// ---------------- K_final: out = M * E_l * E_h ----------------
__global__ void k_final(float* __restrict__ out, const float* __restrict__ EL,
                        const float* __restrict__ EH) {
  int t = blockIdx.x * blockDim.x + threadIdx.x;
  float4 m = ((const float4*)out)[t];
  float4 a = ((const float4*)EL)[t];
  float4 b = ((const float4*)EH)[t];
  m.x *= a.x * b.x; m.y *= a.y * b.y; m.z *= a.z * b.z; m.w *= a.w * b.w;
  ((float4*)out)[t] = m;
}

extern "C" void kernel_launch(void* const* d_in, const int* in_sizes, int n_in,
                              void* d_out, int out_size, void* d_ws, size_t ws_size,
                              hipStream_t stream) {
  const float* sites = (const float*)d_in[0];
  const float* cons  = (const float*)d_in[1];
  const int* idxl = (const int*)d_in[2];
  const int* idxh = (const int*)d_in[3];
  const float* Ws = (const float*)d_in[4];
  const float* bs = (const float*)d_in[5];
  const float* Wc = (const float*)d_in[6];
  const float* bc = (const float*)d_in[7];
  const float* Wd = (const float*)d_in[8];
  const float* bd = (const float*)d_in[9];
  const float* lng = (const float*)d_in[10];
  const float* lnb = (const float*)d_in[11];
  const float* Wo = (const float*)d_in[12];
  const float* bo = (const float*)d_in[13];

  char* wsb = (char*)d_ws;
  size_t o = 0;
  auto alloc = [&](size_t bytes) { char* p = wsb + o; o += (bytes + 15) & ~(size_t)15; return p; };
  float* u   = (float*)alloc((size_t)NS * HH2 * 4);
  float* A   = (float*)alloc((size_t)NS * 4);
  float* P   = (float*)alloc((size_t)NS * 4);
  float* v   = (float*)alloc((size_t)NCC * HH2 * 4);
  float* B   = (float*)alloc((size_t)NCC * 4);
  float* Q   = (float*)alloc((size_t)NCC * 4);
  float* CLp = (float*)alloc((size_t)NS * NCC * 4);
  float* CHp = (float*)alloc((size_t)NS * NCC * 4);
  float* EL  = (float*)alloc((size_t)NS * NCC * 4);
  float* EH  = (float*)alloc((size_t)NS * NCC * 4);
  int* offl  = (int*)alloc((SLOTS + 1) * 4);
  int* slotl = (int*)alloc(NS * 4);
  int* sitel = (int*)alloc(NS * 4);
  int* offh  = (int*)alloc((SLOTS + 1) * 4);
  int* sloth = (int*)alloc(NS * 4);
  int* siteh = (int*)alloc(NS * 4);

  k_setup<<<7, 1024, 0, stream>>>(sites, cons, Ws, bs, Wc, bc, Wd, bd, lng, Wo,
                                  u, A, P, v, B, Q,
                                  idxl, idxh, offl, slotl, sitel, offh, sloth, siteh);
  k_main<<<NS / 16, 1024, 0, stream>>>(u, A, P, v, B, Q, lnb, Wo, bo,
                                       (float*)d_out, CLp, CHp);
  k_band<<<dim3(4, NSEQ, 2), 64, 0, stream>>>(CLp, CHp, offl, slotl, sitel,
                                              offh, sloth, siteh, EL, EH);
  k_final<<<(NS * NCC / 4) / 256, 256, 0, stream>>>((float*)d_out, EL, EH);
}

// Round 4
// 182.222 us; speedup vs baseline: 1.2648x; 1.2648x over previous
//
#include <hip/hip_runtime.h>

#define NS 4096
#define NCC 1024
#define DD 64
#define HH2 32
#define NSEQ 32
#define SLEN 256
#define SLOTS 8192
#define LNEPS 1e-3f
#define MAXSPS 1024   // max sites per sequence (mean 128 — huge margin)

// ---------------- K_setup: blocks 0-4 = prep (5120 rows), blocks 5-6 = counting sort ----------------
__global__ void __launch_bounds__(1024) k_setup(
    const float* __restrict__ sites, const float* __restrict__ cons,
    const float* __restrict__ Ws, const float* __restrict__ bs,
    const float* __restrict__ Wc, const float* __restrict__ bc,
    const float* __restrict__ Wd, const float* __restrict__ bd,
    const float* __restrict__ g, const float* __restrict__ Wo,
    float* __restrict__ u, float* __restrict__ A, float* __restrict__ P,
    float* __restrict__ v, float* __restrict__ B, float* __restrict__ Q,
    const int* __restrict__ idxl, const int* __restrict__ idxh,
    int* __restrict__ offl, int* __restrict__ slotl, int* __restrict__ sitel,
    int* __restrict__ offh, int* __restrict__ sloth, int* __restrict__ siteh) {
  __shared__ int cnt[SLOTS];
  __shared__ int wsumI[16];
  int tid = threadIdx.x;
  if (blockIdx.x < 5) {
    // ---- prep ----
    int t = blockIdx.x * 1024 + tid;
    if (t >= NS + NCC) return;
    bool isSite = t < NS;
    int row = isSite ? t : t - NS;
    const float* x = isSite ? sites + row * DD : cons + row * DD;
    const float* W1 = isSite ? Ws : Wc;
    const float* b1 = isSite ? bs : bc;
    float s[HH2];
#pragma unroll
    for (int h = 0; h < HH2; h++) s[h] = b1[h];
    for (int k = 0; k < DD; k++) {
      float xv = x[k];
#pragma unroll
      for (int h = 0; h < HH2; h++) s[h] = fmaf(xv, W1[k * HH2 + h], s[h]);
    }
#pragma unroll
    for (int h = 0; h < HH2; h++) s[h] = fmaxf(s[h], 0.0f);
    float hs[HH2];
#pragma unroll
    for (int h = 0; h < HH2; h++) hs[h] = isSite ? 0.0f : bd[h];  // b_d folded into con side
    for (int k = 0; k < HH2; k++) {
      float sv = s[k];
#pragma unroll
      for (int h = 0; h < HH2; h++) hs[h] = fmaf(sv, Wd[k * HH2 + h], hs[h]);
    }
    float mu = 0.f;
#pragma unroll
    for (int h = 0; h < HH2; h++) mu += hs[h];
    mu *= (1.0f / HH2);
    float p = 0.f, a = 0.f;
    float* dst = isSite ? (u + row * HH2) : (v + row * HH2);
#pragma unroll
    for (int h = 0; h < HH2; h++) {
      float uu = hs[h] - mu;
      dst[h] = uu;
      p += uu * uu;
      a = fmaf(uu * g[h], Wo[h], a);
    }
    p *= (1.0f / HH2);
    if (isSite) { A[row] = a; P[row] = p; } else { B[row] = a; Q[row] = p; }
    return;
  }
  // ---- sort (blocks 5,6) ----
  int lane = tid & 63, wv = tid >> 6;
  int pass = blockIdx.x - 5;
  const int* idx = pass ? idxh : idxl;
  int* off = pass ? offh : offl;
  int* slotA = pass ? sloth : slotl;
  int* siteA = pass ? siteh : sitel;
  for (int i2 = tid; i2 < SLOTS; i2 += 1024) cnt[i2] = 0;
  __syncthreads();
  for (int i2 = tid; i2 < NS; i2 += 1024) atomicAdd(&cnt[idx[i2]], 1);
  __syncthreads();
  int base = tid * 8;
  int loc[8]; int sum = 0;
#pragma unroll
  for (int q2 = 0; q2 < 8; q2++) { loc[q2] = sum; sum += cnt[base + q2]; }
  int incl = sum;
#pragma unroll
  for (int o = 1; o < 64; o <<= 1) { int t2 = __shfl_up(incl, o); if (lane >= o) incl += t2; }
  if (lane == 63) wsumI[wv] = incl;
  __syncthreads();
  int wprev = 0;
#pragma unroll
  for (int w = 0; w < 16; w++) { int t3 = wsumI[w]; if (w < wv) wprev += t3; }
  int excl = wprev + (incl - sum);
  __syncthreads();
#pragma unroll
  for (int q2 = 0; q2 < 8; q2++) { int o2 = excl + loc[q2]; off[base + q2] = o2; cnt[base + q2] = o2; }
  if (tid == 0) off[SLOTS] = NS;
  __syncthreads();
  for (int i2 = tid; i2 < NS; i2 += 1024) {
    int sl = idx[i2];
    int pos = atomicAdd(&cnt[sl], 1);
    slotA[pos] = sl; siteA[pos] = i2;
  }
}

// ---------------- K_main: logits -> softmax -> cumsums; 16 rows/block, 2 barriers total ----------------
__global__ void __launch_bounds__(1024) k_main(const float* __restrict__ u,
    const float* __restrict__ A, const float* __restrict__ P,
    const float* __restrict__ v, const float* __restrict__ B, const float* __restrict__ Q,
    const float* __restrict__ lnb, const float* __restrict__ Wo, const float* __restrict__ bo,
    float* __restrict__ M, float* __restrict__ CLp, float* __restrict__ CHp) {
  int j = threadIdx.x;
  int lane = j & 63, wv = j >> 6;
  __shared__ float redA[16 * 16];  // [row][wave]
  __shared__ float redB[16 * 16];
  float4 vv[8];
  const float4* vp = (const float4*)(v + j * HH2);
#pragma unroll
  for (int q = 0; q < 8; q++) vv[q] = vp[q];
  float Bj = B[j], Qj = Q[j];
  float C = bo[0];
#pragma unroll
  for (int k = 0; k < HH2; k++) C = fmaf(lnb[k], Wo[k], C);
  int row0 = blockIdx.x * 16;

  float logit[16];
  // Phase 1: all logits + per-wave max
#pragma unroll
  for (int rr = 0; rr < 16; rr++) {
    int i = row0 + rr;
    const float4* up = (const float4*)(u + i * HH2);
    float dot = 0.f;
#pragma unroll
    for (int q = 0; q < 8; q++) {
      float4 u4 = up[q];
      dot = fmaf(u4.x, vv[q].x, dot);
      dot = fmaf(u4.y, vv[q].y, dot);
      dot = fmaf(u4.z, vv[q].z, dot);
      dot = fmaf(u4.w, vv[q].w, dot);
    }
    float var = P[i] + Qj + dot * 0.0625f;   // P + Q + 2*dot/32
    float lg = rsqrtf(var + LNEPS) * (A[i] + Bj) + C;
    logit[rr] = lg;
    float mx = lg;
#pragma unroll
    for (int o = 32; o > 0; o >>= 1) mx = fmaxf(mx, __shfl_xor(mx, o));
    if (lane == 0) redA[rr * 16 + wv] = mx;
  }
  __syncthreads();
  // Phase 2: block max (vector LDS reads), exp, per-wave inclusive scan
  float e[16], incl[16];
#pragma unroll
  for (int rr = 0; rr < 16; rr++) {
    const float4* ra = (const float4*)(redA + rr * 16);
    float4 a0 = ra[0], a1 = ra[1], a2 = ra[2], a3 = ra[3];
    float mx = fmaxf(fmaxf(fmaxf(a0.x, a0.y), fmaxf(a0.z, a0.w)),
                     fmaxf(fmaxf(a1.x, a1.y), fmaxf(a1.z, a1.w)));
    mx = fmaxf(mx, fmaxf(fmaxf(fmaxf(a2.x, a2.y), fmaxf(a2.z, a2.w)),
                         fmaxf(fmaxf(a3.x, a3.y), fmaxf(a3.z, a3.w))));
    float ee = __expf(logit[rr] - mx);
    float ic = ee;
#pragma unroll
    for (int o = 1; o < 64; o <<= 1) { float tt = __shfl_up(ic, o); if (lane >= o) ic += tt; }
    if (lane == 63) redB[rr * 16 + wv] = ic;
    e[rr] = ee; incl[rr] = ic;
  }
  __syncthreads();
  // Phase 3: block prefix/total from wave sums, write M/CL/CH
#pragma unroll
  for (int rr = 0; rr < 16; rr++) {
    const float4* rb = (const float4*)(redB + rr * 16);
    float4 b0 = rb[0], b1 = rb[1], b2 = rb[2], b3 = rb[3];
    float w_[16] = {b0.x, b0.y, b0.z, b0.w, b1.x, b1.y, b1.z, b1.w,
                    b2.x, b2.y, b2.z, b2.w, b3.x, b3.y, b3.z, b3.w};
    float prev = 0.f, tot = 0.f;
#pragma unroll
    for (int w = 0; w < 16; w++) { tot += w_[w]; if (w < wv) prev += w_[w]; }
    float chE = prev + incl[rr];
    float rd = 1.0f / tot;
    int o_ = (row0 + rr) * NCC + j;
    M[o_] = e[rr] * rd;                    // softmax (to d_out)
    CHp[o_] = chE * rd;                    // forward cumsum
    CLp[o_] = (tot - chE + e[rr]) * rd;    // reverse cumsum
  }
}

// ---------------- K_band: walk sorted site list per (band, seq), write excl factors ----------------
// grid = (4 coltiles, 32 seqs, 2 bands), block = 64 threads x 4 cols (float4)
// Double-buffered register tiles (T=8): dedicated load loops with clamped
// indices (no data-dependent control flow) so the compiler emits partial
// vmcnt waits; consume loops guarded by block-uniform cur<n predicate.
__global__ void __launch_bounds__(64, 1) k_band(const float* __restrict__ CLp, const float* __restrict__ CHp,
    const int* __restrict__ offl, const int* __restrict__ slotl, const int* __restrict__ sitel,
    const int* __restrict__ offh, const int* __restrict__ sloth, const int* __restrict__ siteh,
    float* __restrict__ EL, float* __restrict__ EH) {
  int band = blockIdx.z;
  const float* cum = band ? CHp : CLp;
  const int* off   = band ? offh : offl;
  const int* slotA = band ? sloth : slotl;
  const int* siteA = band ? siteh : sitel;
  float* E = band ? EH : EL;
  int seq = blockIdx.y;
  int j0 = blockIdx.x * 256 + threadIdx.x * 4;
  int s0 = off[seq * SLEN];
  int s1 = off[seq * SLEN + SLEN];
  int n = s1 - s0;

  __shared__ int s_site[MAXSPS];
  __shared__ int s_slot[MAXSPS];
  for (int i = threadIdx.x; i < n; i += 64) {
    s_site[i] = siteA[s0 + i];
    s_slot[i] = slotA[s0 + i];
  }
  __syncthreads();
  if (n <= 0) return;

  const int T = 8;
  float4 bufA[T], bufB[T];
#pragma unroll
  for (int k = 0; k < T; k++) {
    int kk = k < n ? k : n - 1;
    bufA[k] = *(const float4*)(cum + (size_t)s_site[kk] * NCC + j0);
  }
#pragma unroll
  for (int k = 0; k < T; k++) {
    int kk = T + k < n ? T + k : n - 1;
    bufB[k] = *(const float4*)(cum + (size_t)s_site[kk] * NCC + j0);
  }

  float4 r = make_float4(1.f, 1.f, 1.f, 1.f);
  float4 z = make_float4(0.f, 0.f, 0.f, 0.f);
  int prev = -1;
  int ntiles = (n + T - 1) / T;
  for (int t = 0; t < ntiles; t += 2) {
    // consume bufA = tile t
#pragma unroll
    for (int k = 0; k < T; k++) {
      int cur = t * T + k;
      if (cur < n) {                       // block-uniform predicate
        float4 cv = bufA[k];
        int slot = s_slot[cur];
        if (slot != prev) {
          if (prev >= 0) {
            r.x *= fmaxf(1.f - z.x, 0.f);
            r.y *= fmaxf(1.f - z.y, 0.f);
            r.z *= fmaxf(1.f - z.z, 0.f);
            r.w *= fmaxf(1.f - z.w, 0.f);
            z = make_float4(0.f, 0.f, 0.f, 0.f);
          }
          prev = slot;
        }
        *(float4*)(E + (size_t)s_site[cur] * NCC + j0) = r;
        z.x += cv.x; z.y += cv.y; z.z += cv.z; z.w += cv.w;
      }
    }
    // refill bufA = tile t+2 (clamped, unconditional)
#pragma unroll
    for (int k = 0; k < T; k++) {
      int idx2 = (t + 2) * T + k;
      int kk = idx2 < n ? idx2 : n - 1;
      bufA[k] = *(const float4*)(cum + (size_t)s_site[kk] * NCC + j0);
    }
    // consume bufB = tile t+1
#pragma unroll
    for (int k = 0; k < T; k++) {
      int cur = (t + 1) * T + k;
      if (cur < n) {
        float4 cv = bufB[k];
        int slot = s_slot[cur];
        if (slot != prev) {
          if (prev >= 0) {
            r.x *= fmaxf(1.f - z.x, 0.f);
            r.y *= fmaxf(1.f - z.y, 0.f);
            r.z *= fmaxf(1.f - z.z, 0.f);
            r.w *= fmaxf(1.f - z.w, 0.f);
            z = make_float4(0.f, 0.f, 0.f, 0.f);
          }
          prev = slot;
        }
        *(float4*)(E + (size_t)s_site[cur] * NCC + j0) = r;
        z.x += cv.x; z.y += cv.y; z.z += cv.z; z.w += cv.w;
      }
    }
    // refill bufB = tile t+3 (clamped, unconditional)
#pragma unroll
    for (int k = 0; k < T; k++) {
      int idx2 = (t + 3) * T + k;
      int kk = idx2 < n ? idx2 : n - 1;
      bufB[k] = *(const float4*)(cum + (size_t)s_site[kk] * NCC + j0);
    }
  }
}

// ---------------- K_final: out = M * E_l * E_h ----------------
__global__ void k_final(float* __restrict__ out, const float* __restrict__ EL,
                        const float* __restrict__ EH) {
  int t = blockIdx.x * blockDim.x + threadIdx.x;
  float4 m = ((const float4*)out)[t];
  float4 a = ((const float4*)EL)[t];
  float4 b = ((const float4*)EH)[t];
  m.x *= a.x * b.x; m.y *= a.y * b.y; m.z *= a.z * b.z; m.w *= a.w * b.w;
  ((float4*)out)[t] = m;
}

extern "C" void kernel_launch(void* const* d_in, const int* in_sizes, int n_in,
                              void* d_out, int out_size, void* d_ws, size_t ws_size,
                              hipStream_t stream) {
  const float* sites = (const float*)d_in[0];
  const float* cons  = (const float*)d_in[1];
  const int* idxl = (const int*)d_in[2];
  const int* idxh = (const int*)d_in[3];
  const float* Ws = (const float*)d_in[4];
  const float* bs = (const float*)d_in[5];
  const float* Wc = (const float*)d_in[6];
  const float* bc = (const float*)d_in[7];
  const float* Wd = (const float*)d_in[8];
  const float* bd = (const float*)d_in[9];
  const float* lng = (const float*)d_in[10];
  const float* lnb = (const float*)d_in[11];
  const float* Wo = (const float*)d_in[12];
  const float* bo = (const float*)d_in[13];

  char* wsb = (char*)d_ws;
  size_t o = 0;
  auto alloc = [&](size_t bytes) { char* p = wsb + o; o += (bytes + 15) & ~(size_t)15; return p; };
  float* u   = (float*)alloc((size_t)NS * HH2 * 4);
  float* A   = (float*)alloc((size_t)NS * 4);
  float* P   = (float*)alloc((size_t)NS * 4);
  float* v   = (float*)alloc((size_t)NCC * HH2 * 4);
  float* B   = (float*)alloc((size_t)NCC * 4);
  float* Q   = (float*)alloc((size_t)NCC * 4);
  float* CLp = (float*)alloc((size_t)NS * NCC * 4);
  float* CHp = (float*)alloc((size_t)NS * NCC * 4);
  float* EL  = (float*)alloc((size_t)NS * NCC * 4);
  float* EH  = (float*)alloc((size_t)NS * NCC * 4);
  int* offl  = (int*)alloc((SLOTS + 1) * 4);
  int* slotl = (int*)alloc(NS * 4);
  int* sitel = (int*)alloc(NS * 4);
  int* offh  = (int*)alloc((SLOTS + 1) * 4);
  int* sloth = (int*)alloc(NS * 4);
  int* siteh = (int*)alloc(NS * 4);

  k_setup<<<7, 1024, 0, stream>>>(sites, cons, Ws, bs, Wc, bc, Wd, bd, lng, Wo,
                                  u, A, P, v, B, Q,
                                  idxl, idxh, offl, slotl, sitel, offh, sloth, siteh);
  k_main<<<NS / 16, 1024, 0, stream>>>(u, A, P, v, B, Q, lnb, Wo, bo,
                                       (float*)d_out, CLp, CHp);
  k_band<<<dim3(4, NSEQ, 2), 64, 0, stream>>>(CLp, CHp, offl, slotl, sitel,
                                              offh, sloth, siteh, EL, EH);
  k_final<<<(NS * NCC / 4) / 256, 256, 0, stream>>>((float*)d_out, EL, EH);
}